// Round 1
// baseline (461.720 us; speedup 1.0000x reference)
//
#include <hip/hip_runtime.h>
#include <hip/hip_bf16.h>

#define DI __device__ __forceinline__

typedef unsigned short u16;
typedef unsigned int u32;
typedef __bf16 bf16x4 __attribute__((ext_vector_type(4)));
typedef __bf16 bf16x8 __attribute__((ext_vector_type(8)));
typedef float f32x4 __attribute__((ext_vector_type(4)));
typedef u16 u16x4 __attribute__((ext_vector_type(4)));
typedef u16 u16x8 __attribute__((ext_vector_type(8)));

// async global->LDS, 16B per lane; LDS dest is wave-uniform base + lane*16
DI void gload16(const void* g, void* l) {
  __builtin_amdgcn_global_load_lds(
      (__attribute__((address_space(1))) void*)(g),
      (__attribute__((address_space(3))) void*)(l), 16, 0, 0);
}

DI u16 f2bf(float f) {  // RNE fp32 -> bf16
  u32 u = __builtin_bit_cast(u32, f);
  return (u16)((u + 0x7fffu + ((u >> 16) & 1u)) >> 16);
}

#define MFMA16(a, b, c) __builtin_amdgcn_mfma_f32_16x16x32_bf16(a, b, c, 0, 0, 0)

// B=4, SQ=SK=2048, HID=1024, NH=16, HD=64
// ---------------- fp32 -> bf16 convert (hidden_states, context) ----------------
__global__ __launch_bounds__(256) void k_convert(const float* __restrict__ a,
                                                 const float* __restrict__ b,
                                                 u16* __restrict__ oa, u16* __restrict__ ob) {
  const float* src = blockIdx.y ? b : a;
  u16* dst = blockIdx.y ? ob : oa;
  const int n4 = (4 * 2048 * 1024) / 4;
  for (int i = blockIdx.x * blockDim.x + threadIdx.x; i < n4; i += gridDim.x * blockDim.x) {
    float4 v = ((const float4*)src)[i];
    u16x4 o;
    o[0] = f2bf(v.x); o[1] = f2bf(v.y); o[2] = f2bf(v.z); o[3] = f2bf(v.w);
    *(u16x4*)(dst + 4 * (size_t)i) = o;
  }
}

// ---------------- weights: Wt[z][n][k] = W[k][n], fp32 -> bf16 ----------------
__global__ __launch_bounds__(256) void k_transW(const float* __restrict__ Wq,
                                                const float* __restrict__ Wk,
                                                const float* __restrict__ Wv,
                                                u16* __restrict__ Wt) {
  __shared__ u16 tile[64][72];
  const float* W = blockIdx.z == 0 ? Wq : (blockIdx.z == 1 ? Wk : Wv);
  u16* out = Wt + (size_t)blockIdx.z * (1024 * 1024);
  int k0 = blockIdx.x * 64, n0 = blockIdx.y * 64;
  int t = threadIdx.x, r = t >> 2, c0 = (t & 3) * 16;
  const float4* src = (const float4*)(W + (size_t)(k0 + r) * 1024 + n0 + c0);
#pragma unroll
  for (int i = 0; i < 4; ++i) {
    float4 v = src[i];
    tile[r][c0 + 4 * i + 0] = f2bf(v.x); tile[r][c0 + 4 * i + 1] = f2bf(v.y);
    tile[r][c0 + 4 * i + 2] = f2bf(v.z); tile[r][c0 + 4 * i + 3] = f2bf(v.w);
  }
  __syncthreads();
  u16x8 o0, o1;
#pragma unroll
  for (int i = 0; i < 8; ++i) { o0[i] = tile[c0 + i][r]; o1[i] = tile[c0 + 8 + i][r]; }
  u16* dst = out + (size_t)(n0 + r) * 1024 + k0 + c0;
  *(u16x8*)dst = o0; *(u16x8*)(dst + 8) = o1;
}

// ---------------- GEMM: C[m][n] = A[m][:]·Bt[n][:] + bias[n], scatter to [B][NH][S][64] ----
// 128x128 tile, BK=32, 4 waves 2x2 (64x64 each), dbuf LDS via global_load_lds(16B),
// source-chunk XOR swizzle (c ^= row&3) so frag ds_read_b128 is ~conflict-free.
__global__ __launch_bounds__(256) void k_gemm(const u16* __restrict__ A,
                                              const u16* __restrict__ Bt,
                                              const float* __restrict__ bias,
                                              u16* __restrict__ C) {
  __shared__ __attribute__((aligned(16))) u16 As[2][128 * 32];
  __shared__ __attribute__((aligned(16))) u16 Bs[2][128 * 32];
  const int t = threadIdx.x, w = t >> 6, l = t & 63, g = l >> 4, lid = l & 15;
  const int wr = w >> 1, wc = w & 1;
  const int m0 = blockIdx.x * 128, n0 = blockIdx.y * 128;
  f32x4 acc[4][4] = {};

  auto stage = [&](int buf, int kt) {
    for (int i = 0; i < 2; ++i) {
      int slot = i * 256 + t;            // 512 slots = 128 rows x 4 chunks(16B)
      int row = slot >> 2, c = slot & 3;
      gload16(A + (size_t)(m0 + row) * 1024 + kt * 32 + ((c ^ (row & 3)) << 3),
              &As[buf][slot << 3]);
      gload16(Bt + (size_t)(n0 + row) * 1024 + kt * 32 + ((c ^ (row & 3)) << 3),
              &Bs[buf][slot << 3]);
    }
  };

  stage(0, 0);
  __syncthreads();
  int cur = 0;
  for (int kt = 0; kt < 32; ++kt) {
    if (kt + 1 < 32) stage(cur ^ 1, kt + 1);
    bf16x8 af[4], bfr[4];
#pragma unroll
    for (int mi = 0; mi < 4; ++mi) {
      int row = wr * 64 + mi * 16 + lid;
      af[mi] = *(const bf16x8*)&As[cur][(row << 5) + ((g ^ (row & 3)) << 3)];
    }
#pragma unroll
    for (int ni = 0; ni < 4; ++ni) {
      int row = wc * 64 + ni * 16 + lid;
      bfr[ni] = *(const bf16x8*)&Bs[cur][(row << 5) + ((g ^ (row & 3)) << 3)];
    }
#pragma unroll
    for (int mi = 0; mi < 4; ++mi)
#pragma unroll
      for (int ni = 0; ni < 4; ++ni)
        acc[mi][ni] = MFMA16(af[mi], bfr[ni], acc[mi][ni]);
    __syncthreads();
    cur ^= 1;
  }
  // epilogue: +bias, bf16, scatter C[m][n] -> out[(b*16+h)][s][d]
#pragma unroll
  for (int ni = 0; ni < 4; ++ni) {
    int n = n0 + wc * 64 + ni * 16 + lid;
    float bb = bias[n];
    int h = n >> 6, d = n & 63;
#pragma unroll
    for (int mi = 0; mi < 4; ++mi) {
      int mb = m0 + wr * 64 + mi * 16 + g * 4;
#pragma unroll
      for (int j = 0; j < 4; ++j) {
        int m = mb + j;
        int b = m >> 11, s = m & 2047;
        C[((size_t)(b * 16 + h) << 17) + ((size_t)s << 6) + d] = f2bf(acc[mi][ni][j] + bb);
      }
    }
  }
}

// ---------------- V [head][2048][64] -> Vt [head][64][2048] ----------------
__global__ __launch_bounds__(256) void k_transV(const u16* __restrict__ V,
                                                u16* __restrict__ Vt) {
  __shared__ u16 tile[64][72];
  int h = blockIdx.y, s0 = blockIdx.x * 64;
  int t = threadIdx.x, r = t >> 2, c0 = (t & 3) * 16;
  const u16x8* src = (const u16x8*)(V + (size_t)h * 131072 + (size_t)(s0 + r) * 64 + c0);
  u16x8 a = src[0], b = src[1];
#pragma unroll
  for (int i = 0; i < 8; ++i) { tile[r][c0 + i] = a[i]; tile[r][c0 + 8 + i] = b[i]; }
  __syncthreads();
  u16x8 o0, o1;
#pragma unroll
  for (int i = 0; i < 8; ++i) { o0[i] = tile[c0 + i][r]; o1[i] = tile[c0 + 8 + i][r]; }
  u16* dst = Vt + (size_t)h * 131072 + (size_t)r * 2048 + s0 + c0;
  *(u16x8*)dst = o0; *(u16x8*)(dst + 8) = o1;
}

// ---------------- flash attention ----------------
// block = 4 waves, 128 q-rows (32/wave), KBLK=64, K/V dbuf in LDS via gload16+swizzle,
// online softmax in fp32, P bounced through wave-private padded LDS (stride 72 = 9x16B).
__global__ __launch_bounds__(256) void k_attn(const u16* __restrict__ Q,
                                              const u16* __restrict__ K,
                                              const u16* __restrict__ Vt,
                                              float* __restrict__ Out) {
  __shared__ __attribute__((aligned(16))) u16 smem[25600];  // 51200 B
  u16* Ks = smem;                              // [2][64*64]
  u16* Vs = smem + 8192;                       // [2][64*64] (V^T tiles: [hd][kv])
  __bf16* Pw_base = (__bf16*)(smem + 16384);   // [4][32*72]
  const int t = threadIdx.x, w = t >> 6, l = t & 63, g = l >> 4, lid = l & 15;
  const int head = blockIdx.y, q0 = blockIdx.x * 128;
  const size_t hoff = (size_t)head * 131072;
  const u16* Qh = Q + hoff + (size_t)q0 * 64;
  const u16* Kh = K + hoff;
  const u16* Vh = Vt + hoff;                   // [64][2048]
  __bf16* Pw = Pw_base + w * 2304;

  // stage Q tile (128x64) into smem[0..8191] (region later reused by K dbuf)
  for (int i = 0; i < 4; ++i) {
    int slot = i * 256 + t;
    int row = slot >> 3, c = slot & 7;
    gload16(Qh + (size_t)row * 64 + ((c ^ (row & 7)) << 3), &smem[slot << 3]);
  }
  __syncthreads();
  bf16x8 qa[2][2];
#pragma unroll
  for (int mi = 0; mi < 2; ++mi)
#pragma unroll
    for (int ks = 0; ks < 2; ++ks) {
      int row = w * 32 + mi * 16 + lid;
      int c = ks * 4 + g;
      qa[mi][ks] = *(const bf16x8*)&smem[(row << 6) + ((c ^ (row & 7)) << 3)];
    }
  __syncthreads();  // Q reads done before K staging overwrites

  auto stageKV = [&](int buf, int kv0) {
    for (int i = 0; i < 2; ++i) {
      int slot = i * 256 + t;            // 512 slots = 64 rows x 8 chunks
      int row = slot >> 3, c = slot & 7;
      gload16(Kh + (size_t)(kv0 + row) * 64 + ((c ^ (row & 7)) << 3),
              &Ks[buf * 4096 + (slot << 3)]);
      gload16(Vh + (size_t)row * 2048 + kv0 + ((c ^ (row & 7)) << 3),
              &Vs[buf * 4096 + (slot << 3)]);
    }
  };

  f32x4 o[2][4] = {};
  float mrun[2][4], lrun[2][4];
#pragma unroll
  for (int mi = 0; mi < 2; ++mi)
#pragma unroll
    for (int j = 0; j < 4; ++j) { mrun[mi][j] = -1e30f; lrun[mi][j] = 0.f; }

  stageKV(0, 0);
  __syncthreads();
  int cur = 0;
  const float CC = 0.18033688011112042f;  // log2(e) / sqrt(HD)=8
  for (int tt = 0; tt < 32; ++tt) {
    if (tt + 1 < 32) stageKV(cur ^ 1, (tt + 1) * 64);
    // S = Q K^T  (rows q in regs j / lane-groups, cols kv in lid)
    f32x4 s[2][4] = {};
#pragma unroll
    for (int ks = 0; ks < 2; ++ks) {
      bf16x8 kb[4];
#pragma unroll
      for (int ni = 0; ni < 4; ++ni) {
        int row = ni * 16 + lid;
        int c = ks * 4 + g;
        kb[ni] = *(const bf16x8*)&Ks[cur * 4096 + (row << 6) + ((c ^ (row & 7)) << 3)];
      }
#pragma unroll
      for (int mi = 0; mi < 2; ++mi)
#pragma unroll
        for (int ni = 0; ni < 4; ++ni)
          s[mi][ni] = MFMA16(qa[mi][ks], kb[ni], s[mi][ni]);
    }
    // online softmax (per q-row: 4 in-reg frags + 16-lane shfl reduce)
#pragma unroll
    for (int mi = 0; mi < 2; ++mi)
#pragma unroll
      for (int j = 0; j < 4; ++j) {
        float rm = fmaxf(fmaxf(s[mi][0][j], s[mi][1][j]), fmaxf(s[mi][2][j], s[mi][3][j]));
        rm = fmaxf(rm, __shfl_xor(rm, 1, 64));
        rm = fmaxf(rm, __shfl_xor(rm, 2, 64));
        rm = fmaxf(rm, __shfl_xor(rm, 4, 64));
        rm = fmaxf(rm, __shfl_xor(rm, 8, 64));
        float mnew = fmaxf(mrun[mi][j], rm);
        float scale = exp2f((mrun[mi][j] - mnew) * CC);
        mrun[mi][j] = mnew;
        float rs = 0.f;
#pragma unroll
        for (int ni = 0; ni < 4; ++ni) {
          float p = exp2f((s[mi][ni][j] - mnew) * CC);
          s[mi][ni][j] = p;
          rs += p;
        }
        rs += __shfl_xor(rs, 1, 64);
        rs += __shfl_xor(rs, 2, 64);
        rs += __shfl_xor(rs, 4, 64);
        rs += __shfl_xor(rs, 8, 64);
        lrun[mi][j] = lrun[mi][j] * scale + rs;
#pragma unroll
        for (int hf = 0; hf < 4; ++hf) o[mi][hf][j] *= scale;
      }
    // P -> wave-private LDS (bf16), then PV
#pragma unroll
    for (int mi = 0; mi < 2; ++mi)
#pragma unroll
      for (int ni = 0; ni < 4; ++ni)
#pragma unroll
        for (int j = 0; j < 4; ++j)
          Pw[(mi * 16 + g * 4 + j) * 72 + ni * 16 + lid] = (__bf16)s[mi][ni][j];
    asm volatile("" ::: "memory");
#pragma unroll
    for (int ks = 0; ks < 2; ++ks) {
      bf16x8 vb[4];
#pragma unroll
      for (int hf = 0; hf < 4; ++hf) {
        int row = hf * 16 + lid;
        int c = ks * 4 + g;
        vb[hf] = *(const bf16x8*)&Vs[cur * 4096 + (row << 6) + ((c ^ (row & 7)) << 3)];
      }
#pragma unroll
      for (int mi = 0; mi < 2; ++mi) {
        bf16x8 pa = *(const bf16x8*)&Pw[(mi * 16 + lid) * 72 + ks * 32 + g * 8];
#pragma unroll
        for (int hf = 0; hf < 4; ++hf)
          o[mi][hf] = MFMA16(pa, vb[hf], o[mi][hf]);
      }
    }
    __syncthreads();
    cur ^= 1;
  }
  // epilogue: out[b][q][h*64 + hd] fp32
  const int b = head >> 4, h = head & 15;
#pragma unroll
  for (int mi = 0; mi < 2; ++mi)
#pragma unroll
    for (int j = 0; j < 4; ++j) {
      int q = q0 + w * 32 + mi * 16 + g * 4 + j;
      float inv = 1.f / lrun[mi][j];
      float* op = Out + ((size_t)b * 2048 + q) * 1024 + h * 64 + lid;
#pragma unroll
      for (int hf = 0; hf < 4; ++hf) op[hf * 16] = o[mi][hf][j] * inv;
    }
}

extern "C" void kernel_launch(void* const* d_in, const int* in_sizes, int n_in,
                              void* d_out, int out_size, void* d_ws, size_t ws_size,
                              hipStream_t stream) {
  const float* hs  = (const float*)d_in[0];
  const float* ctx = (const float*)d_in[1];
  const float* Wq  = (const float*)d_in[2];
  const float* bq  = (const float*)d_in[3];
  const float* Wk  = (const float*)d_in[4];
  const float* bk  = (const float*)d_in[5];
  const float* Wv  = (const float*)d_in[6];
  const float* bv  = (const float*)d_in[7];
  float* out = (float*)d_out;

  // workspace layout (u16 elems): hs_bf | ctx_bf | Wt(3) | Q | K | Vt ; V reuses hs_bf
  u16* hsb  = (u16*)d_ws;            // 8388608
  u16* ctxb = hsb + 8388608;         // 8388608
  u16* Wt   = ctxb + 8388608;        // 3*1048576
  u16* Qb   = Wt + 3 * 1048576;      // 8388608
  u16* Kb   = Qb + 8388608;          // 8388608
  u16* Vtb  = Kb + 8388608;          // 8388608
  u16* Vb   = hsb;                   // alias: hs_bf dead after Q-GEMM

  k_convert<<<dim3(2048, 2), 256, 0, stream>>>(hs, ctx, hsb, ctxb);
  k_transW<<<dim3(16, 16, 3), 256, 0, stream>>>(Wq, Wk, Wv, Wt);
  k_gemm<<<dim3(64, 8), 256, 0, stream>>>(hsb, Wt, bq, Qb);
  k_gemm<<<dim3(64, 8), 256, 0, stream>>>(ctxb, Wt + 1048576, bk, Kb);
  k_gemm<<<dim3(64, 8), 256, 0, stream>>>(ctxb, Wt + 2097152, bv, Vb);
  k_transV<<<dim3(32, 64), 256, 0, stream>>>(Vb, Vtb);
  k_attn<<<dim3(16, 64), 256, 0, stream>>>(Qb, Kb, Vtb, out);
}

// Round 4
// 356.017 us; speedup vs baseline: 1.2969x; 1.2969x over previous
//
#include <hip/hip_runtime.h>
#include <hip/hip_bf16.h>
#include <math.h>

#define DI __device__ __forceinline__

typedef unsigned short u16;
typedef unsigned int u32;
typedef __bf16 bf16x8 __attribute__((ext_vector_type(8)));
typedef float f32x4 __attribute__((ext_vector_type(4)));
typedef float f32x16 __attribute__((ext_vector_type(16)));
typedef u16 u16x4 __attribute__((ext_vector_type(4)));
typedef u16 u16x8 __attribute__((ext_vector_type(8)));
typedef u32 u32x4 __attribute__((ext_vector_type(4)));

// async global->LDS, 16B per lane; LDS dest is wave-uniform base + lane*16
DI void gload16(const void* g, void* l) {
  __builtin_amdgcn_global_load_lds(
      (__attribute__((address_space(1))) void*)(g),
      (__attribute__((address_space(3))) void*)(l), 16, 0, 0);
}

DI u16 f2bf(float f) {  // RNE fp32 -> bf16
  u32 u = __builtin_bit_cast(u32, f);
  return (u16)((u + 0x7fffu + ((u >> 16) & 1u)) >> 16);
}

DI u32 cvtpk(float lo, float hi_) {  // bf16(lo) | bf16(hi)<<16 (plain VALU, no hazard class)
  u32 r; asm("v_cvt_pk_bf16_f32 %0, %1, %2" : "=v"(r) : "v"(lo), "v"(hi_)); return r;
}

#define MFMA16(a, b, c) __builtin_amdgcn_mfma_f32_16x16x32_bf16(a, b, c, 0, 0, 0)
#define MFMA32(a, b, c) __builtin_amdgcn_mfma_f32_32x32x16_bf16(a, b, c, 0, 0, 0)

// B=4, SQ=SK=2048, HID=1024, NH=16, HD=64
// ---------------- fp32 -> bf16 convert (hidden_states, context) ----------------
__global__ __launch_bounds__(256) void k_convert(const float* __restrict__ a,
                                                 const float* __restrict__ b,
                                                 u16* __restrict__ oa, u16* __restrict__ ob) {
  const float* src = blockIdx.y ? b : a;
  u16* dst = blockIdx.y ? ob : oa;
  const int n4 = (4 * 2048 * 1024) / 4;
  for (int i = blockIdx.x * blockDim.x + threadIdx.x; i < n4; i += gridDim.x * blockDim.x) {
    float4 v = ((const float4*)src)[i];
    u16x4 o;
    o[0] = f2bf(v.x); o[1] = f2bf(v.y); o[2] = f2bf(v.z); o[3] = f2bf(v.w);
    *(u16x4*)(dst + 4 * (size_t)i) = o;
  }
}

// ---------------- weights: Wt[z][n][k] = W[k][n], fp32 -> bf16 ----------------
__global__ __launch_bounds__(256) void k_transW(const float* __restrict__ Wq,
                                                const float* __restrict__ Wk,
                                                const float* __restrict__ Wv,
                                                u16* __restrict__ Wt) {
  __shared__ u16 tile[64][72];
  const float* W = blockIdx.z == 0 ? Wq : (blockIdx.z == 1 ? Wk : Wv);
  u16* out = Wt + (size_t)blockIdx.z * (1024 * 1024);
  int k0 = blockIdx.x * 64, n0 = blockIdx.y * 64;
  int t = threadIdx.x, r = t >> 2, c0 = (t & 3) * 16;
  const float4* src = (const float4*)(W + (size_t)(k0 + r) * 1024 + n0 + c0);
#pragma unroll
  for (int i = 0; i < 4; ++i) {
    float4 v = src[i];
    tile[r][c0 + 4 * i + 0] = f2bf(v.x); tile[r][c0 + 4 * i + 1] = f2bf(v.y);
    tile[r][c0 + 4 * i + 2] = f2bf(v.z); tile[r][c0 + 4 * i + 3] = f2bf(v.w);
  }
  __syncthreads();
  u16x8 o0, o1;
#pragma unroll
  for (int i = 0; i < 8; ++i) { o0[i] = tile[c0 + i][r]; o1[i] = tile[c0 + 8 + i][r]; }
  u16* dst = out + (size_t)(n0 + r) * 1024 + k0 + c0;
  *(u16x8*)dst = o0; *(u16x8*)(dst + 8) = o1;
}

// ---------------- GEMM: C[m][n] = (A[m][:]·Bt[n][:] + bias[n])*scale -> [B][NH][S][64] ----
__global__ __launch_bounds__(256) void k_gemm(const u16* __restrict__ A,
                                              const u16* __restrict__ Bt,
                                              const float* __restrict__ bias,
                                              u16* __restrict__ C, float scale) {
  __shared__ __attribute__((aligned(16))) u16 As[2][128 * 32];
  __shared__ __attribute__((aligned(16))) u16 Bs[2][128 * 32];
  const int t = threadIdx.x, w = t >> 6, l = t & 63, g = l >> 4, lid = l & 15;
  const int wr = w >> 1, wc = w & 1;
  const int m0 = blockIdx.x * 128, n0 = blockIdx.y * 128;
  f32x4 acc[4][4] = {};

  auto stage = [&](int buf, int kt) {
    for (int i = 0; i < 2; ++i) {
      int slot = i * 256 + t;            // 512 slots = 128 rows x 4 chunks(16B)
      int row = slot >> 2, c = slot & 3;
      gload16(A + (size_t)(m0 + row) * 1024 + kt * 32 + ((c ^ (row & 3)) << 3),
              &As[buf][slot << 3]);
      gload16(Bt + (size_t)(n0 + row) * 1024 + kt * 32 + ((c ^ (row & 3)) << 3),
              &Bs[buf][slot << 3]);
    }
  };

  stage(0, 0);
  __syncthreads();
  int cur = 0;
  for (int kt = 0; kt < 32; ++kt) {
    if (kt + 1 < 32) stage(cur ^ 1, kt + 1);
    bf16x8 af[4], bfr[4];
#pragma unroll
    for (int mi = 0; mi < 4; ++mi) {
      int row = wr * 64 + mi * 16 + lid;
      af[mi] = *(const bf16x8*)&As[cur][(row << 5) + ((g ^ (row & 3)) << 3)];
    }
#pragma unroll
    for (int ni = 0; ni < 4; ++ni) {
      int row = wc * 64 + ni * 16 + lid;
      bfr[ni] = *(const bf16x8*)&Bs[cur][(row << 5) + ((g ^ (row & 3)) << 3)];
    }
#pragma unroll
    for (int mi = 0; mi < 4; ++mi)
#pragma unroll
      for (int ni = 0; ni < 4; ++ni)
        acc[mi][ni] = MFMA16(af[mi], bfr[ni], acc[mi][ni]);
    __syncthreads();
    cur ^= 1;
  }
#pragma unroll
  for (int ni = 0; ni < 4; ++ni) {
    int n = n0 + wc * 64 + ni * 16 + lid;
    float bb = bias[n];
    int h = n >> 6, d = n & 63;
#pragma unroll
    for (int mi = 0; mi < 4; ++mi) {
      int mb = m0 + wr * 64 + mi * 16 + g * 4;
#pragma unroll
      for (int j = 0; j < 4; ++j) {
        int m = mb + j;
        int b = m >> 11, s = m & 2047;
        C[((size_t)(b * 16 + h) << 17) + ((size_t)s << 6) + d] =
            f2bf((acc[mi][ni][j] + bb) * scale);
      }
    }
  }
}

// ---------------- V [head][2048][64] -> Vt [head][64][2048] ----------------
__global__ __launch_bounds__(256) void k_transV(const u16* __restrict__ V,
                                                u16* __restrict__ Vt) {
  __shared__ u16 tile[64][72];
  int h = blockIdx.y, s0 = blockIdx.x * 64;
  int t = threadIdx.x, r = t >> 2, c0 = (t & 3) * 16;
  const u16x8* src = (const u16x8*)(V + (size_t)h * 131072 + (size_t)(s0 + r) * 64 + c0);
  u16x8 a = src[0], b = src[1];
#pragma unroll
  for (int i = 0; i < 8; ++i) { tile[r][c0 + i] = a[i]; tile[r][c0 + 8 + i] = b[i]; }
  __syncthreads();
  u16x8 o0, o1;
#pragma unroll
  for (int i = 0; i < 8; ++i) { o0[i] = tile[c0 + i][r]; o1[i] = tile[c0 + 8 + i][r]; }
  u16* dst = Vt + (size_t)h * 131072 + (size_t)r * 2048 + s0 + c0;
  *(u16x8*)dst = o0; *(u16x8*)(dst + 8) = o1;
}

// ---------------- flash attention, 32x32 swapped-QK^T, in-register softmax ----------------
// 4 waves x 32 q-rows, KVBLK=64. S^T = mfma(K, Q): lane&31 = q, full row state in-lane
// (kv split across lane-pair l / l+32 per the crow C/D layout).
// Cross-half exchange via __shfl_xor(.,32) (direction-certain); P packed via cvt_pk_bf16.
// Q pre-scaled by log2e/8 in k_gemm so S is in log2 domain; defer-max THR=8.
__global__ __launch_bounds__(256) void k_attn(const u16* __restrict__ Q,
                                              const u16* __restrict__ K,
                                              const u16* __restrict__ Vt,
                                              float* __restrict__ Out) {
  __shared__ __attribute__((aligned(16))) u16 smem[16384];  // 32KB: Ks[2][4096] | Vs[2][4096]
  u16* Ks = smem;
  u16* Vs = smem + 8192;
  const int t = threadIdx.x, w = t >> 6, l = t & 63;
  const int ql = l & 31, hi = l >> 5;
  const int head = blockIdx.y, q0 = blockIdx.x * 128;
  const size_t hoff = (size_t)head * 131072;
  const u16* Qh = Q + hoff + (size_t)q0 * 64;
  const u16* Kh = K + hoff;
  const u16* Vh = Vt + hoff;  // [64][2048]

  // stage Q tile (128x64) into Ks region (reused after frag extraction)
  for (int i = 0; i < 4; ++i) {
    int slot = i * 256 + t, row = slot >> 3, c = slot & 7;
    gload16(Qh + (size_t)row * 64 + ((c ^ (row & 7)) << 3), &smem[slot << 3]);
  }
  __syncthreads();
  bf16x8 qf[4];  // B-frags: col q = ql, d = dt*16 + hi*8 + i
  const int qrow = w * 32 + ql;
#pragma unroll
  for (int dt = 0; dt < 4; ++dt) {
    int ch = dt * 2 + hi;
    qf[dt] = *(const bf16x8*)&smem[(qrow << 6) + ((ch ^ (qrow & 7)) << 3)];
  }
  __syncthreads();

  auto stageKV = [&](int buf, int kv0) {
    for (int i = 0; i < 2; ++i) {
      int slot = i * 256 + t, row = slot >> 3, c = slot & 7;
      gload16(Kh + (size_t)(kv0 + row) * 64 + ((c ^ (row & 7)) << 3),
              &Ks[buf * 4096 + (slot << 3)]);
      gload16(Vh + (size_t)row * 2048 + kv0 + ((c ^ (row & 7)) << 3),
              &Vs[buf * 4096 + (slot << 3)]);
    }
  };

  f32x16 ot0 = {}, ot1 = {};       // O^T: col q = ql; row d = (r&3)+8*(r>>2)+4*hi (+32 for ot1)
  float m = -1e30f, lsum = 0.f;

  stageKV(0, 0);
  __syncthreads();
  int cur = 0;
  for (int tt = 0; tt < 32; ++tt) {
    if (tt + 1 < 32) stageKV(cur ^ 1, (tt + 1) * 64);
    const u16* Kb = &Ks[cur * 4096];
    const u16* Vb = &Vs[cur * 4096];
    // S^T[kv][q]: A = K-tile rows, B = Q frags
    f32x16 st0 = {}, st1 = {};
#pragma unroll
    for (int dt = 0; dt < 4; ++dt) {
      int ch = dt * 2 + hi;
      {
        int row = ql;
        bf16x8 kf = *(const bf16x8*)&Kb[(row << 6) + ((ch ^ (row & 7)) << 3)];
        st0 = MFMA32(kf, qf[dt], st0);
      }
      {
        int row = 32 + ql;
        bf16x8 kf = *(const bf16x8*)&Kb[(row << 6) + ((ch ^ (row & 7)) << 3)];
        st1 = MFMA32(kf, qf[dt], st1);
      }
    }
    // in-register online softmax (log2 domain); combine lane-pair halves via shfl_xor 32
    float rm = st0[0];
#pragma unroll
    for (int r = 1; r < 16; ++r) rm = fmaxf(rm, st0[r]);
#pragma unroll
    for (int r = 0; r < 16; ++r) rm = fmaxf(rm, st1[r]);
    rm = fmaxf(rm, __shfl_xor(rm, 32, 64));
    if (!__all(rm <= m + 8.f)) {   // defer-max (T13)
      float mn = fmaxf(m, rm);
      float sc = exp2f(m - mn);
      m = mn;
#pragma unroll
      for (int r = 0; r < 16; ++r) { ot0[r] *= sc; ot1[r] *= sc; }
      lsum *= sc;
    }
    float rs = 0.f;
#pragma unroll
    for (int r = 0; r < 16; ++r) { st0[r] = exp2f(st0[r] - m); rs += st0[r]; }
#pragma unroll
    for (int r = 0; r < 16; ++r) { st1[r] = exp2f(st1[r] - m); rs += st1[r]; }
    rs += __shfl_xor(rs, 32, 64);
    lsum += rs;
    // PV: per 16-kv chunk build P B-frag (k = 8*hi + i) via cvt_pk + partner shfl + select.
    // own cvtpk pairs: a0=crow(0,1) a1=crow(2,3) b0=crow(4,5) b1=crow(6,7)
    //   hi=0 lane: a0=kv01 a1=kv23 b0=kv89 b1=kv10,11
    //   hi=1 lane: a0=kv45 a1=kv67 b0=kv12,13 b1=kv14,15
#define PVCHUNK(sp, rb, c)                                                    \
    do {                                                                      \
      u32 a0 = cvtpk(sp[rb + 0], sp[rb + 1]);                                 \
      u32 a1 = cvtpk(sp[rb + 2], sp[rb + 3]);                                 \
      u32 b0 = cvtpk(sp[rb + 4], sp[rb + 5]);                                 \
      u32 b1 = cvtpk(sp[rb + 6], sp[rb + 7]);                                 \
      u32 pa0 = __shfl_xor(a0, 32, 64);                                       \
      u32 pa1 = __shfl_xor(a1, 32, 64);                                       \
      u32 pb0 = __shfl_xor(b0, 32, 64);                                       \
      u32 pb1 = __shfl_xor(b1, 32, 64);                                       \
      u32x4 pw;                                                               \
      pw[0] = hi ? pb0 : a0;   /* kv 8hi+0,1 */                               \
      pw[1] = hi ? pb1 : a1;   /* kv 8hi+2,3 */                               \
      pw[2] = hi ? b0 : pa0;   /* kv 8hi+4,5 */                               \
      pw[3] = hi ? b1 : pa1;   /* kv 8hi+6,7 */                               \
      bf16x8 pf = __builtin_bit_cast(bf16x8, pw);                             \
      {                                                                       \
        int row = ql, ch = (c) * 2 + hi;                                      \
        bf16x8 vf = *(const bf16x8*)&Vb[(row << 6) + ((ch ^ (row & 7)) << 3)];\
        ot0 = MFMA32(vf, pf, ot0);                                            \
      }                                                                       \
      {                                                                       \
        int row = 32 + ql, ch = (c) * 2 + hi;                                 \
        bf16x8 vf = *(const bf16x8*)&Vb[(row << 6) + ((ch ^ (row & 7)) << 3)];\
        ot1 = MFMA32(vf, pf, ot1);                                            \
      }                                                                       \
    } while (0)
    PVCHUNK(st0, 0, 0);
    PVCHUNK(st0, 8, 1);
    PVCHUNK(st1, 0, 2);
    PVCHUNK(st1, 8, 3);
#undef PVCHUNK
    __syncthreads();
    cur ^= 1;
  }
  // epilogue: out[b][q][h*64 + d], d = dt*32 + rq*8 + 4*hi + j
  const int b = head >> 4, h = head & 15;
  const int qg = q0 + w * 32 + ql;
  float inv = 1.f / lsum;
  float* op = Out + ((size_t)b * 2048 + qg) * 1024 + h * 64;
#pragma unroll
  for (int rq = 0; rq < 4; ++rq) {
    f32x4 v0, v1;
#pragma unroll
    for (int j = 0; j < 4; ++j) {
      v0[j] = ot0[rq * 4 + j] * inv;
      v1[j] = ot1[rq * 4 + j] * inv;
    }
    *(f32x4*)(op + rq * 8 + 4 * hi) = v0;
    *(f32x4*)(op + 32 + rq * 8 + 4 * hi) = v1;
  }
}

extern "C" void kernel_launch(void* const* d_in, const int* in_sizes, int n_in,
                              void* d_out, int out_size, void* d_ws, size_t ws_size,
                              hipStream_t stream) {
  const float* hs  = (const float*)d_in[0];
  const float* ctx = (const float*)d_in[1];
  const float* Wq  = (const float*)d_in[2];
  const float* bq  = (const float*)d_in[3];
  const float* Wk  = (const float*)d_in[4];
  const float* bk  = (const float*)d_in[5];
  const float* Wv  = (const float*)d_in[6];
  const float* bv  = (const float*)d_in[7];
  float* out = (float*)d_out;

  u16* hsb  = (u16*)d_ws;            // 8388608
  u16* ctxb = hsb + 8388608;         // 8388608
  u16* Wt   = ctxb + 8388608;        // 3*1048576
  u16* Qb   = Wt + 3 * 1048576;      // 8388608
  u16* Kb   = Qb + 8388608;          // 8388608
  u16* Vtb  = Kb + 8388608;          // 8388608
  u16* Vb   = hsb;                   // alias: hs_bf dead after Q-GEMM

  const float CC = 0.18033688011112042f;  // log2(e)/sqrt(HD=64)

  k_convert<<<dim3(2048, 2), 256, 0, stream>>>(hs, ctx, hsb, ctxb);
  k_transW<<<dim3(16, 16, 3), 256, 0, stream>>>(Wq, Wk, Wv, Wt);
  k_gemm<<<dim3(64, 8), 256, 0, stream>>>(hsb, Wt, bq, Qb, CC);
  k_gemm<<<dim3(64, 8), 256, 0, stream>>>(ctxb, Wt + 1048576, bk, Kb, 1.0f);
  k_gemm<<<dim3(64, 8), 256, 0, stream>>>(ctxb, Wt + 2097152, bv, Vb, 1.0f);
  k_transV<<<dim3(32, 64), 256, 0, stream>>>(Vb, Vtb);
  k_attn<<<dim3(16, 64), 256, 0, stream>>>(Qb, Kb, Vtb, out);
}

// Round 6
// 351.568 us; speedup vs baseline: 1.3133x; 1.0127x over previous
//
#include <hip/hip_runtime.h>
#include <hip/hip_bf16.h>
#include <math.h>

#define DI __device__ __forceinline__

typedef unsigned short u16;
typedef unsigned int u32;
typedef __bf16 bf16x8 __attribute__((ext_vector_type(8)));
typedef float f32x4 __attribute__((ext_vector_type(4)));
typedef float f32x16 __attribute__((ext_vector_type(16)));
typedef u16 u16x4 __attribute__((ext_vector_type(4)));
typedef u16 u16x8 __attribute__((ext_vector_type(8)));
typedef u32 u32x4 __attribute__((ext_vector_type(4)));

// async global->LDS, 16B per lane; LDS dest is wave-uniform base + lane*16
DI void gload16(const void* g, void* l) {
  __builtin_amdgcn_global_load_lds(
      (__attribute__((address_space(1))) void*)(g),
      (__attribute__((address_space(3))) void*)(l), 16, 0, 0);
}

DI u16 f2bf(float f) {  // RNE fp32 -> bf16
  u32 u = __builtin_bit_cast(u32, f);
  return (u16)((u + 0x7fffu + ((u >> 16) & 1u)) >> 16);
}

DI u32 cvtpk(float lo, float hi_) {  // bf16(lo) | bf16(hi)<<16 (plain VALU, no hazard class)
  u32 r; asm("v_cvt_pk_bf16_f32 %0, %1, %2" : "=v"(r) : "v"(lo), "v"(hi_)); return r;
}

#define MFMA16(a, b, c) __builtin_amdgcn_mfma_f32_16x16x32_bf16(a, b, c, 0, 0, 0)
#define MFMA32(a, b, c) __builtin_amdgcn_mfma_f32_32x32x16_bf16(a, b, c, 0, 0, 0)

// B=4, SQ=SK=2048, HID=1024, NH=16, HD=64
// ---------------- fp32 -> bf16 convert (hidden_states, context) ----------------
__global__ __launch_bounds__(256) void k_convert(const float* __restrict__ a,
                                                 const float* __restrict__ b,
                                                 u16* __restrict__ oa, u16* __restrict__ ob) {
  const float* src = blockIdx.y ? b : a;
  u16* dst = blockIdx.y ? ob : oa;
  const int n4 = (4 * 2048 * 1024) / 4;
  for (int i = blockIdx.x * blockDim.x + threadIdx.x; i < n4; i += gridDim.x * blockDim.x) {
    float4 v = ((const float4*)src)[i];
    u16x4 o;
    o[0] = f2bf(v.x); o[1] = f2bf(v.y); o[2] = f2bf(v.z); o[3] = f2bf(v.w);
    *(u16x4*)(dst + 4 * (size_t)i) = o;
  }
}

// ---------------- weights: Wt[z][n][k] = W[k][n], fp32 -> bf16 ----------------
__global__ __launch_bounds__(256) void k_transW(const float* __restrict__ Wq,
                                                const float* __restrict__ Wk,
                                                const float* __restrict__ Wv,
                                                u16* __restrict__ Wt) {
  __shared__ u16 tile[64][72];
  const float* W = blockIdx.z == 0 ? Wq : (blockIdx.z == 1 ? Wk : Wv);
  u16* out = Wt + (size_t)blockIdx.z * (1024 * 1024);
  int k0 = blockIdx.x * 64, n0 = blockIdx.y * 64;
  int t = threadIdx.x, r = t >> 2, c0 = (t & 3) * 16;
  const float4* src = (const float4*)(W + (size_t)(k0 + r) * 1024 + n0 + c0);
#pragma unroll
  for (int i = 0; i < 4; ++i) {
    float4 v = src[i];
    tile[r][c0 + 4 * i + 0] = f2bf(v.x); tile[r][c0 + 4 * i + 1] = f2bf(v.y);
    tile[r][c0 + 4 * i + 2] = f2bf(v.z); tile[r][c0 + 4 * i + 3] = f2bf(v.w);
  }
  __syncthreads();
  u16x8 o0, o1;
#pragma unroll
  for (int i = 0; i < 8; ++i) { o0[i] = tile[c0 + i][r]; o1[i] = tile[c0 + 8 + i][r]; }
  u16* dst = out + (size_t)(n0 + r) * 1024 + k0 + c0;
  *(u16x8*)dst = o0; *(u16x8*)(dst + 8) = o1;
}

// ---------------- GEMM: C[m][n] = (A[m][:]·Bt[n][:] + bias[n])*scale ----------------
// vt=0: scatter to [B][NH][S][64].  vt=1: scatter TRANSPOSED to Vt[head][64][2048].
__global__ __launch_bounds__(256) void k_gemm(const u16* __restrict__ A,
                                              const u16* __restrict__ Bt,
                                              const float* __restrict__ bias,
                                              u16* __restrict__ C, float scale, int vt) {
  __shared__ __attribute__((aligned(16))) u16 As[2][128 * 32];
  __shared__ __attribute__((aligned(16))) u16 Bs[2][128 * 32];
  const int t = threadIdx.x, w = t >> 6, l = t & 63, g = l >> 4, lid = l & 15;
  const int wr = w >> 1, wc = w & 1;
  const int m0 = blockIdx.x * 128, n0 = blockIdx.y * 128;
  f32x4 acc[4][4] = {};

  auto stage = [&](int buf, int kt) {
    for (int i = 0; i < 2; ++i) {
      int slot = i * 256 + t;            // 512 slots = 128 rows x 4 chunks(16B)
      int row = slot >> 2, c = slot & 3;
      gload16(A + (size_t)(m0 + row) * 1024 + kt * 32 + ((c ^ (row & 3)) << 3),
              &As[buf][slot << 3]);
      gload16(Bt + (size_t)(n0 + row) * 1024 + kt * 32 + ((c ^ (row & 3)) << 3),
              &Bs[buf][slot << 3]);
    }
  };

  stage(0, 0);
  __syncthreads();
  int cur = 0;
  for (int kt = 0; kt < 32; ++kt) {
    if (kt + 1 < 32) stage(cur ^ 1, kt + 1);
    bf16x8 af[4], bfr[4];
#pragma unroll
    for (int mi = 0; mi < 4; ++mi) {
      int row = wr * 64 + mi * 16 + lid;
      af[mi] = *(const bf16x8*)&As[cur][(row << 5) + ((g ^ (row & 3)) << 3)];
    }
#pragma unroll
    for (int ni = 0; ni < 4; ++ni) {
      int row = wc * 64 + ni * 16 + lid;
      bfr[ni] = *(const bf16x8*)&Bs[cur][(row << 5) + ((g ^ (row & 3)) << 3)];
    }
#pragma unroll
    for (int mi = 0; mi < 4; ++mi)
#pragma unroll
      for (int ni = 0; ni < 4; ++ni)
        acc[mi][ni] = MFMA16(af[mi], bfr[ni], acc[mi][ni]);
    __syncthreads();
    cur ^= 1;
  }
#pragma unroll
  for (int ni = 0; ni < 4; ++ni) {
    int n = n0 + wc * 64 + ni * 16 + lid;
    float bb = bias[n];
    int h = n >> 6, d = n & 63;
#pragma unroll
    for (int mi = 0; mi < 4; ++mi) {
      int mb = m0 + wr * 64 + mi * 16 + g * 4;
      if (vt) {
        // Vt[(b*16+h)][d][s], s = mb+j consecutive -> one 8B store
        int b = mb >> 11, sl = mb & 2047;
        u16x4 o;
#pragma unroll
        for (int j = 0; j < 4; ++j) o[j] = f2bf((acc[mi][ni][j] + bb) * scale);
        *(u16x4*)&C[(size_t)(b * 16 + h) * 131072 + (size_t)d * 2048 + sl] = o;
      } else {
#pragma unroll
        for (int j = 0; j < 4; ++j) {
          int m = mb + j;
          int b = m >> 11, s = m & 2047;
          C[((size_t)(b * 16 + h) << 17) + ((size_t)s << 6) + d] =
              f2bf((acc[mi][ni][j] + bb) * scale);
        }
      }
    }
  }
}

// ---------------- flash attention, 32x32 swapped-QK^T, in-register softmax ----------------
// 4 waves x 32 q-rows, KVBLK=64. S^T = mfma(K, Q): lane&31 = q, full row state in-lane
// (kv split across lane-pair l / l+32 per the crow C/D layout).
// Cross-half exchange via __shfl_xor(.,32) (proven round 4); P packed via cvt_pk_bf16.
// Tree-shaped max/sum reductions (depth 5 instead of serial 31).
// Q pre-scaled by log2e/8 in k_gemm so S is in log2 domain; defer-max THR=8.
__global__ __launch_bounds__(256) void k_attn(const u16* __restrict__ Q,
                                              const u16* __restrict__ K,
                                              const u16* __restrict__ Vt,
                                              float* __restrict__ Out) {
  __shared__ __attribute__((aligned(16))) u16 smem[16384];  // 32KB: Ks[2][4096] | Vs[2][4096]
  u16* Ks = smem;
  u16* Vs = smem + 8192;
  const int t = threadIdx.x, w = t >> 6, l = t & 63;
  const int ql = l & 31, hi = l >> 5;
  const int head = blockIdx.y, q0 = blockIdx.x * 128;
  const size_t hoff = (size_t)head * 131072;
  const u16* Qh = Q + hoff + (size_t)q0 * 64;
  const u16* Kh = K + hoff;
  const u16* Vh = Vt + hoff;  // [64][2048]

  // stage Q tile (128x64) into Ks region (reused after frag extraction)
  for (int i = 0; i < 4; ++i) {
    int slot = i * 256 + t, row = slot >> 3, c = slot & 7;
    gload16(Qh + (size_t)row * 64 + ((c ^ (row & 7)) << 3), &smem[slot << 3]);
  }
  __syncthreads();
  bf16x8 qf[4];  // B-frags: col q = ql, d = dt*16 + hi*8 + i
  const int qrow = w * 32 + ql;
#pragma unroll
  for (int dt = 0; dt < 4; ++dt) {
    int ch = dt * 2 + hi;
    qf[dt] = *(const bf16x8*)&smem[(qrow << 6) + ((ch ^ (qrow & 7)) << 3)];
  }
  __syncthreads();

  auto stageKV = [&](int buf, int kv0) {
    for (int i = 0; i < 2; ++i) {
      int slot = i * 256 + t, row = slot >> 3, c = slot & 7;
      gload16(Kh + (size_t)(kv0 + row) * 64 + ((c ^ (row & 7)) << 3),
              &Ks[buf * 4096 + (slot << 3)]);
      gload16(Vh + (size_t)row * 2048 + kv0 + ((c ^ (row & 7)) << 3),
              &Vs[buf * 4096 + (slot << 3)]);
    }
  };

  f32x16 ot0 = {}, ot1 = {};       // O^T: col q = ql; row d = (r&3)+8*(r>>2)+4*hi (+32 for ot1)
  float m = -1e30f, lsum = 0.f;

  stageKV(0, 0);
  __syncthreads();
  int cur = 0;
  for (int tt = 0; tt < 32; ++tt) {
    if (tt + 1 < 32) stageKV(cur ^ 1, (tt + 1) * 64);
    const u16* Kb = &Ks[cur * 4096];
    const u16* Vb = &Vs[cur * 4096];
    // S^T[kv][q]: A = K-tile rows, B = Q frags
    f32x16 st0 = {}, st1 = {};
#pragma unroll
    for (int dt = 0; dt < 4; ++dt) {
      int ch = dt * 2 + hi;
      {
        int row = ql;
        bf16x8 kf = *(const bf16x8*)&Kb[(row << 6) + ((ch ^ (row & 7)) << 3)];
        st0 = MFMA32(kf, qf[dt], st0);
      }
      {
        int row = 32 + ql;
        bf16x8 kf = *(const bf16x8*)&Kb[(row << 6) + ((ch ^ (row & 7)) << 3)];
        st1 = MFMA32(kf, qf[dt], st1);
      }
    }
    // in-register online softmax (log2 domain): depth-5 max tree (v_max3-fusable)
    float mx[16];
#pragma unroll
    for (int r = 0; r < 16; ++r) mx[r] = fmaxf(st0[r], st1[r]);
#pragma unroll
    for (int s = 8; s; s >>= 1)
#pragma unroll
      for (int r = 0; r < s; ++r) mx[r] = fmaxf(mx[r], mx[r + s]);
    float rm = mx[0];
    rm = fmaxf(rm, __shfl_xor(rm, 32, 64));
    if (!__all(rm <= m + 8.f)) {   // defer-max (T13)
      float mn = fmaxf(m, rm);
      float sc = exp2f(m - mn);
      m = mn;
#pragma unroll
      for (int r = 0; r < 16; ++r) { ot0[r] *= sc; ot1[r] *= sc; }
      lsum *= sc;
    }
#pragma unroll
    for (int r = 0; r < 16; ++r) st0[r] = exp2f(st0[r] - m);
#pragma unroll
    for (int r = 0; r < 16; ++r) st1[r] = exp2f(st1[r] - m);
    // depth-5 sum tree
    float sm[16];
#pragma unroll
    for (int r = 0; r < 16; ++r) sm[r] = st0[r] + st1[r];
#pragma unroll
    for (int s = 8; s; s >>= 1)
#pragma unroll
      for (int r = 0; r < s; ++r) sm[r] += sm[r + s];
    float rs = sm[0];
    rs += __shfl_xor(rs, 32, 64);
    lsum += rs;
    // PV: per 16-kv chunk build P B-frag (k = 8*hi + i) via cvt_pk + partner shfl + select.
    // own cvtpk pairs: a0=crow(0,1) a1=crow(2,3) b0=crow(4,5) b1=crow(6,7)
    //   hi=0 lane: a0=kv01 a1=kv23 b0=kv89 b1=kv10,11
    //   hi=1 lane: a0=kv45 a1=kv67 b0=kv12,13 b1=kv14,15
#define PVCHUNK(sp, rb, c)                                                    \
    do {                                                                      \
      u32 a0 = cvtpk(sp[rb + 0], sp[rb + 1]);                                 \
      u32 a1 = cvtpk(sp[rb + 2], sp[rb + 3]);                                 \
      u32 b0 = cvtpk(sp[rb + 4], sp[rb + 5]);                                 \
      u32 b1 = cvtpk(sp[rb + 6], sp[rb + 7]);                                 \
      u32 pa0 = __shfl_xor(a0, 32, 64);                                       \
      u32 pa1 = __shfl_xor(a1, 32, 64);                                       \
      u32 pb0 = __shfl_xor(b0, 32, 64);                                       \
      u32 pb1 = __shfl_xor(b1, 32, 64);                                       \
      u32x4 pw;                                                               \
      pw[0] = hi ? pb0 : a0;   /* kv 8hi+0,1 */                               \
      pw[1] = hi ? pb1 : a1;   /* kv 8hi+2,3 */                               \
      pw[2] = hi ? b0 : pa0;   /* kv 8hi+4,5 */                               \
      pw[3] = hi ? b1 : pa1;   /* kv 8hi+6,7 */                               \
      bf16x8 pf = __builtin_bit_cast(bf16x8, pw);                             \
      {                                                                       \
        int row = ql, ch = (c) * 2 + hi;                                      \
        bf16x8 vf = *(const bf16x8*)&Vb[(row << 6) + ((ch ^ (row & 7)) << 3)];\
        ot0 = MFMA32(vf, pf, ot0);                                            \
      }                                                                       \
      {                                                                       \
        int row = 32 + ql, ch = (c) * 2 + hi;                                 \
        bf16x8 vf = *(const bf16x8*)&Vb[(row << 6) + ((ch ^ (row & 7)) << 3)];\
        ot1 = MFMA32(vf, pf, ot1);                                            \
      }                                                                       \
    } while (0)
    PVCHUNK(st0, 0, 0);
    PVCHUNK(st0, 8, 1);
    PVCHUNK(st1, 0, 2);
    PVCHUNK(st1, 8, 3);
#undef PVCHUNK
    __syncthreads();
    cur ^= 1;
  }
  // epilogue: out[b][q][h*64 + d], d = dt*32 + rq*8 + 4*hi + j
  const int b = head >> 4, h = head & 15;
  const int qg = q0 + w * 32 + ql;
  float inv = 1.f / lsum;
  float* op = Out + ((size_t)b * 2048 + qg) * 1024 + h * 64;
#pragma unroll
  for (int rq = 0; rq < 4; ++rq) {
    f32x4 v0, v1;
#pragma unroll
    for (int j = 0; j < 4; ++j) {
      v0[j] = ot0[rq * 4 + j] * inv;
      v1[j] = ot1[rq * 4 + j] * inv;
    }
    *(f32x4*)(op + rq * 8 + 4 * hi) = v0;
    *(f32x4*)(op + 32 + rq * 8 + 4 * hi) = v1;
  }
}

extern "C" void kernel_launch(void* const* d_in, const int* in_sizes, int n_in,
                              void* d_out, int out_size, void* d_ws, size_t ws_size,
                              hipStream_t stream) {
  const float* hs  = (const float*)d_in[0];
  const float* ctx = (const float*)d_in[1];
  const float* Wq  = (const float*)d_in[2];
  const float* bq  = (const float*)d_in[3];
  const float* Wk  = (const float*)d_in[4];
  const float* bk  = (const float*)d_in[5];
  const float* Wv  = (const float*)d_in[6];
  const float* bv  = (const float*)d_in[7];
  float* out = (float*)d_out;

  u16* hsb  = (u16*)d_ws;            // 8388608
  u16* ctxb = hsb + 8388608;         // 8388608
  u16* Wt   = ctxb + 8388608;        // 3*1048576
  u16* Qb   = Wt + 3 * 1048576;      // 8388608
  u16* Kb   = Qb + 8388608;          // 8388608
  u16* Vtb  = Kb + 8388608;          // 8388608

  const float CC = 0.18033688011112042f;  // log2(e)/sqrt(HD=64)

  k_convert<<<dim3(2048, 2), 256, 0, stream>>>(hs, ctx, hsb, ctxb);
  k_transW<<<dim3(16, 16, 3), 256, 0, stream>>>(Wq, Wk, Wv, Wt);
  k_gemm<<<dim3(64, 8), 256, 0, stream>>>(hsb, Wt, bq, Qb, CC, 0);
  k_gemm<<<dim3(64, 8), 256, 0, stream>>>(ctxb, Wt + 1048576, bk, Kb, 1.0f, 0);
  k_gemm<<<dim3(64, 8), 256, 0, stream>>>(ctxb, Wt + 2097152, bv, Vtb, 1.0f, 1);
  k_attn<<<dim3(16, 64), 256, 0, stream>>>(Qb, Kb, Vtb, out);
}

// Round 7
// 324.082 us; speedup vs baseline: 1.4247x; 1.0848x over previous
//
#include <hip/hip_runtime.h>
#include <hip/hip_bf16.h>
#include <math.h>

#define DI __device__ __forceinline__

typedef unsigned short u16;
typedef unsigned int u32;
typedef __bf16 bf16x8 __attribute__((ext_vector_type(8)));
typedef float f32x4 __attribute__((ext_vector_type(4)));
typedef float f32x16 __attribute__((ext_vector_type(16)));
typedef u16 u16x4 __attribute__((ext_vector_type(4)));
typedef u16 u16x8 __attribute__((ext_vector_type(8)));
typedef u32 u32x4 __attribute__((ext_vector_type(4)));

// async global->LDS, 16B per lane; LDS dest is wave-uniform base + lane*16
DI void gload16(const void* g, void* l) {
  __builtin_amdgcn_global_load_lds(
      (__attribute__((address_space(1))) void*)(g),
      (__attribute__((address_space(3))) void*)(l), 16, 0, 0);
}

DI u16 f2bf(float f) {  // RNE fp32 -> bf16
  u32 u = __builtin_bit_cast(u32, f);
  return (u16)((u + 0x7fffu + ((u >> 16) & 1u)) >> 16);
}

DI u32 cvtpk(float lo, float hi_) {  // bf16(lo) | bf16(hi)<<16 (plain VALU, no hazard class)
  u32 r; asm("v_cvt_pk_bf16_f32 %0, %1, %2" : "=v"(r) : "v"(lo), "v"(hi_)); return r;
}

#define MFMA16(a, b, c) __builtin_amdgcn_mfma_f32_16x16x32_bf16(a, b, c, 0, 0, 0)
#define MFMA32(a, b, c) __builtin_amdgcn_mfma_f32_32x32x16_bf16(a, b, c, 0, 0, 0)

// B=4, SQ=SK=2048, HID=1024, NH=16, HD=64
// ---------------- fp32 -> bf16 convert (hidden_states, context) ----------------
__global__ __launch_bounds__(256) void k_convert(const float* __restrict__ a,
                                                 const float* __restrict__ b,
                                                 u16* __restrict__ oa, u16* __restrict__ ob) {
  const float* src = blockIdx.y ? b : a;
  u16* dst = blockIdx.y ? ob : oa;
  const int n4 = (4 * 2048 * 1024) / 4;
  for (int i = blockIdx.x * blockDim.x + threadIdx.x; i < n4; i += gridDim.x * blockDim.x) {
    float4 v = ((const float4*)src)[i];
    u16x4 o;
    o[0] = f2bf(v.x); o[1] = f2bf(v.y); o[2] = f2bf(v.z); o[3] = f2bf(v.w);
    *(u16x4*)(dst + 4 * (size_t)i) = o;
  }
}

// ---------------- weights: Wt[z][n][k] = W[k][n], fp32 -> bf16 ----------------
__global__ __launch_bounds__(256) void k_transW(const float* __restrict__ Wq,
                                                const float* __restrict__ Wk,
                                                const float* __restrict__ Wv,
                                                u16* __restrict__ Wt) {
  __shared__ u16 tile[64][72];
  const float* W = blockIdx.z == 0 ? Wq : (blockIdx.z == 1 ? Wk : Wv);
  u16* out = Wt + (size_t)blockIdx.z * (1024 * 1024);
  int k0 = blockIdx.x * 64, n0 = blockIdx.y * 64;
  int t = threadIdx.x, r = t >> 2, c0 = (t & 3) * 16;
  const float4* src = (const float4*)(W + (size_t)(k0 + r) * 1024 + n0 + c0);
#pragma unroll
  for (int i = 0; i < 4; ++i) {
    float4 v = src[i];
    tile[r][c0 + 4 * i + 0] = f2bf(v.x); tile[r][c0 + 4 * i + 1] = f2bf(v.y);
    tile[r][c0 + 4 * i + 2] = f2bf(v.z); tile[r][c0 + 4 * i + 3] = f2bf(v.w);
  }
  __syncthreads();
  u16x8 o0, o1;
#pragma unroll
  for (int i = 0; i < 8; ++i) { o0[i] = tile[c0 + i][r]; o1[i] = tile[c0 + 8 + i][r]; }
  u16* dst = out + (size_t)(n0 + r) * 1024 + k0 + c0;
  *(u16x8*)dst = o0; *(u16x8*)(dst + 8) = o1;
}

// ---------------- fused QKV GEMM: z selects {A, W, bias, C, scale, layout} ----------------
// C[m][n] = (A[m][:]·Bt[n][:] + bias[n])*scale
// z=0: Q from hs -> [B][NH][S][64] (*CC); z=1: K from ctx -> same; z=2: V from ctx -> Vt[head][64][2048]
__global__ __launch_bounds__(256) void k_gemm(const u16* __restrict__ hsb,
                                              const u16* __restrict__ ctxb,
                                              const u16* __restrict__ Wt,
                                              const float* __restrict__ bq,
                                              const float* __restrict__ bk,
                                              const float* __restrict__ bv,
                                              u16* __restrict__ Qb, u16* __restrict__ Kb,
                                              u16* __restrict__ Vtb, float CC) {
  const int z = blockIdx.z;
  const u16* A = z ? ctxb : hsb;
  const u16* Bt = Wt + (size_t)z * 1048576;
  const float* bias = z == 0 ? bq : (z == 1 ? bk : bv);
  u16* C = z == 0 ? Qb : (z == 1 ? Kb : Vtb);
  const float scale = z == 0 ? CC : 1.0f;
  const int vt = (z == 2);

  __shared__ __attribute__((aligned(16))) u16 As[2][128 * 32];
  __shared__ __attribute__((aligned(16))) u16 Bs[2][128 * 32];
  const int t = threadIdx.x, w = t >> 6, l = t & 63, g = l >> 4, lid = l & 15;
  const int wr = w >> 1, wc = w & 1;
  const int m0 = blockIdx.x * 128, n0 = blockIdx.y * 128;
  f32x4 acc[4][4] = {};

  auto stage = [&](int buf, int kt) {
    for (int i = 0; i < 2; ++i) {
      int slot = i * 256 + t;            // 512 slots = 128 rows x 4 chunks(16B)
      int row = slot >> 2, c = slot & 3;
      gload16(A + (size_t)(m0 + row) * 1024 + kt * 32 + ((c ^ (row & 3)) << 3),
              &As[buf][slot << 3]);
      gload16(Bt + (size_t)(n0 + row) * 1024 + kt * 32 + ((c ^ (row & 3)) << 3),
              &Bs[buf][slot << 3]);
    }
  };

  stage(0, 0);
  __syncthreads();
  int cur = 0;
  for (int kt = 0; kt < 32; ++kt) {
    if (kt + 1 < 32) stage(cur ^ 1, kt + 1);
    bf16x8 af[4], bfr[4];
#pragma unroll
    for (int mi = 0; mi < 4; ++mi) {
      int row = wr * 64 + mi * 16 + lid;
      af[mi] = *(const bf16x8*)&As[cur][(row << 5) + ((g ^ (row & 3)) << 3)];
    }
#pragma unroll
    for (int ni = 0; ni < 4; ++ni) {
      int row = wc * 64 + ni * 16 + lid;
      bfr[ni] = *(const bf16x8*)&Bs[cur][(row << 5) + ((g ^ (row & 3)) << 3)];
    }
    __builtin_amdgcn_s_setprio(1);
#pragma unroll
    for (int mi = 0; mi < 4; ++mi)
#pragma unroll
      for (int ni = 0; ni < 4; ++ni)
        acc[mi][ni] = MFMA16(af[mi], bfr[ni], acc[mi][ni]);
    __builtin_amdgcn_s_setprio(0);
    __syncthreads();
    cur ^= 1;
  }
#pragma unroll
  for (int ni = 0; ni < 4; ++ni) {
    int n = n0 + wc * 64 + ni * 16 + lid;
    float bb = bias[n];
    int h = n >> 6, d = n & 63;
#pragma unroll
    for (int mi = 0; mi < 4; ++mi) {
      int mb = m0 + wr * 64 + mi * 16 + g * 4;
      if (vt) {
        // Vt[(b*16+h)][d][s], s = mb+j consecutive -> one 8B store
        int b = mb >> 11, sl = mb & 2047;
        u16x4 o;
#pragma unroll
        for (int j = 0; j < 4; ++j) o[j] = f2bf((acc[mi][ni][j] + bb) * scale);
        *(u16x4*)&C[(size_t)(b * 16 + h) * 131072 + (size_t)d * 2048 + sl] = o;
      } else {
#pragma unroll
        for (int j = 0; j < 4; ++j) {
          int m = mb + j;
          int b = m >> 11, s = m & 2047;
          C[((size_t)(b * 16 + h) << 17) + ((size_t)s << 6) + d] =
              f2bf((acc[mi][ni][j] + bb) * scale);
        }
      }
    }
  }
}

// ---------------- flash attention, 32x32 swapped-QK^T, in-register softmax ----------------
// 4 waves x 32 q-rows, KVBLK=64. S^T = mfma(K, Q): lane&31 = q, full row state in-lane
// (kv split across lane-pair l / l+32 per the crow C/D layout).
// Cross-half exchange via __shfl_xor(.,32); P packed via cvt_pk_bf16.
// launch_bounds(256,4): force 4 waves/EU (4 blocks/CU) so VALU of one block hides
// under MFMA of another (m114 co-schedule). setprio around MFMA clusters (T5).
// Q pre-scaled by log2e/8 in k_gemm so S is in log2 domain; defer-max THR=8.
__global__ __launch_bounds__(256, 4) void k_attn(const u16* __restrict__ Q,
                                                 const u16* __restrict__ K,
                                                 const u16* __restrict__ Vt,
                                                 float* __restrict__ Out) {
  __shared__ __attribute__((aligned(16))) u16 smem[16384];  // 32KB: Ks[2][4096] | Vs[2][4096]
  u16* Ks = smem;
  u16* Vs = smem + 8192;
  const int t = threadIdx.x, w = t >> 6, l = t & 63;
  const int ql = l & 31, hi = l >> 5;
  const int head = blockIdx.y, q0 = blockIdx.x * 128;
  const size_t hoff = (size_t)head * 131072;
  const u16* Qh = Q + hoff + (size_t)q0 * 64;
  const u16* Kh = K + hoff;
  const u16* Vh = Vt + hoff;  // [64][2048]

  // stage Q tile (128x64) into Ks region (reused after frag extraction)
  for (int i = 0; i < 4; ++i) {
    int slot = i * 256 + t, row = slot >> 3, c = slot & 7;
    gload16(Qh + (size_t)row * 64 + ((c ^ (row & 7)) << 3), &smem[slot << 3]);
  }
  __syncthreads();
  bf16x8 qf[4];  // B-frags: col q = ql, d = dt*16 + hi*8 + i
  const int qrow = w * 32 + ql;
#pragma unroll
  for (int dt = 0; dt < 4; ++dt) {
    int ch = dt * 2 + hi;
    qf[dt] = *(const bf16x8*)&smem[(qrow << 6) + ((ch ^ (qrow & 7)) << 3)];
  }
  __syncthreads();

  auto stageKV = [&](int buf, int kv0) {
    for (int i = 0; i < 2; ++i) {
      int slot = i * 256 + t, row = slot >> 3, c = slot & 7;
      gload16(Kh + (size_t)(kv0 + row) * 64 + ((c ^ (row & 7)) << 3),
              &Ks[buf * 4096 + (slot << 3)]);
      gload16(Vh + (size_t)row * 2048 + kv0 + ((c ^ (row & 7)) << 3),
              &Vs[buf * 4096 + (slot << 3)]);
    }
  };

  f32x16 ot0 = {}, ot1 = {};       // O^T: col q = ql; row d = (r&3)+8*(r>>2)+4*hi (+32 for ot1)
  float m = -1e30f, lsum = 0.f;

  stageKV(0, 0);
  __syncthreads();
  int cur = 0;
  for (int tt = 0; tt < 32; ++tt) {
    if (tt + 1 < 32) stageKV(cur ^ 1, (tt + 1) * 64);
    const u16* Kb = &Ks[cur * 4096];
    const u16* Vb = &Vs[cur * 4096];
    // S^T[kv][q]: A = K-tile rows, B = Q frags
    f32x16 st0 = {}, st1 = {};
    __builtin_amdgcn_s_setprio(1);
#pragma unroll
    for (int dt = 0; dt < 4; ++dt) {
      int ch = dt * 2 + hi;
      {
        int row = ql;
        bf16x8 kf = *(const bf16x8*)&Kb[(row << 6) + ((ch ^ (row & 7)) << 3)];
        st0 = MFMA32(kf, qf[dt], st0);
      }
      {
        int row = 32 + ql;
        bf16x8 kf = *(const bf16x8*)&Kb[(row << 6) + ((ch ^ (row & 7)) << 3)];
        st1 = MFMA32(kf, qf[dt], st1);
      }
    }
    __builtin_amdgcn_s_setprio(0);
    // in-register online softmax (log2 domain): depth-5 max tree (v_max3-fusable)
    float mx[16];
#pragma unroll
    for (int r = 0; r < 16; ++r) mx[r] = fmaxf(st0[r], st1[r]);
#pragma unroll
    for (int s = 8; s; s >>= 1)
#pragma unroll
      for (int r = 0; r < s; ++r) mx[r] = fmaxf(mx[r], mx[r + s]);
    float rm = mx[0];
    rm = fmaxf(rm, __shfl_xor(rm, 32, 64));
    if (!__all(rm <= m + 8.f)) {   // defer-max (T13)
      float mn = fmaxf(m, rm);
      float sc = exp2f(m - mn);
      m = mn;
#pragma unroll
      for (int r = 0; r < 16; ++r) { ot0[r] *= sc; ot1[r] *= sc; }
      lsum *= sc;
    }
#pragma unroll
    for (int r = 0; r < 16; ++r) st0[r] = exp2f(st0[r] - m);
#pragma unroll
    for (int r = 0; r < 16; ++r) st1[r] = exp2f(st1[r] - m);
    // depth-5 sum tree
    float sm[16];
#pragma unroll
    for (int r = 0; r < 16; ++r) sm[r] = st0[r] + st1[r];
#pragma unroll
    for (int s = 8; s; s >>= 1)
#pragma unroll
      for (int r = 0; r < s; ++r) sm[r] += sm[r + s];
    float rs = sm[0];
    rs += __shfl_xor(rs, 32, 64);
    lsum += rs;
    // PV: per 16-kv chunk build P B-frag (k = 8*hi + i) via cvt_pk + partner shfl + select.
#define PVCHUNK(sp, rb, c)                                                    \
    do {                                                                      \
      u32 a0 = cvtpk(sp[rb + 0], sp[rb + 1]);                                 \
      u32 a1 = cvtpk(sp[rb + 2], sp[rb + 3]);                                 \
      u32 b0 = cvtpk(sp[rb + 4], sp[rb + 5]);                                 \
      u32 b1 = cvtpk(sp[rb + 6], sp[rb + 7]);                                 \
      u32 pa0 = __shfl_xor(a0, 32, 64);                                       \
      u32 pa1 = __shfl_xor(a1, 32, 64);                                       \
      u32 pb0 = __shfl_xor(b0, 32, 64);                                       \
      u32 pb1 = __shfl_xor(b1, 32, 64);                                       \
      u32x4 pw;                                                               \
      pw[0] = hi ? pb0 : a0;   /* kv 8hi+0,1 */                               \
      pw[1] = hi ? pb1 : a1;   /* kv 8hi+2,3 */                               \
      pw[2] = hi ? b0 : pa0;   /* kv 8hi+4,5 */                               \
      pw[3] = hi ? b1 : pa1;   /* kv 8hi+6,7 */                               \
      bf16x8 pf = __builtin_bit_cast(bf16x8, pw);                             \
      __builtin_amdgcn_s_setprio(1);                                          \
      {                                                                       \
        int row = ql, ch = (c) * 2 + hi;                                      \
        bf16x8 vf = *(const bf16x8*)&Vb[(row << 6) + ((ch ^ (row & 7)) << 3)];\
        ot0 = MFMA32(vf, pf, ot0);                                            \
      }                                                                       \
      {                                                                       \
        int row = 32 + ql, ch = (c) * 2 + hi;                                 \
        bf16x8 vf = *(const bf16x8*)&Vb[(row << 6) + ((ch ^ (row & 7)) << 3)];\
        ot1 = MFMA32(vf, pf, ot1);                                            \
      }                                                                       \
      __builtin_amdgcn_s_setprio(0);                                          \
    } while (0)
    PVCHUNK(st0, 0, 0);
    PVCHUNK(st0, 8, 1);
    PVCHUNK(st1, 0, 2);
    PVCHUNK(st1, 8, 3);
#undef PVCHUNK
    __syncthreads();
    cur ^= 1;
  }
  // epilogue: out[b][q][h*64 + d], d = dt*32 + rq*8 + 4*hi + j
  const int b = head >> 4, h = head & 15;
  const int qg = q0 + w * 32 + ql;
  float inv = 1.f / lsum;
  float* op = Out + ((size_t)b * 2048 + qg) * 1024 + h * 64;
#pragma unroll
  for (int rq = 0; rq < 4; ++rq) {
    f32x4 v0, v1;
#pragma unroll
    for (int j = 0; j < 4; ++j) {
      v0[j] = ot0[rq * 4 + j] * inv;
      v1[j] = ot1[rq * 4 + j] * inv;
    }
    *(f32x4*)(op + rq * 8 + 4 * hi) = v0;
    *(f32x4*)(op + 32 + rq * 8 + 4 * hi) = v1;
  }
}

extern "C" void kernel_launch(void* const* d_in, const int* in_sizes, int n_in,
                              void* d_out, int out_size, void* d_ws, size_t ws_size,
                              hipStream_t stream) {
  const float* hs  = (const float*)d_in[0];
  const float* ctx = (const float*)d_in[1];
  const float* Wq  = (const float*)d_in[2];
  const float* bq  = (const float*)d_in[3];
  const float* Wk  = (const float*)d_in[4];
  const float* bk  = (const float*)d_in[5];
  const float* Wv  = (const float*)d_in[6];
  const float* bv  = (const float*)d_in[7];
  float* out = (float*)d_out;

  u16* hsb  = (u16*)d_ws;            // 8388608
  u16* ctxb = hsb + 8388608;         // 8388608
  u16* Wt   = ctxb + 8388608;        // 3*1048576
  u16* Qb   = Wt + 3 * 1048576;      // 8388608
  u16* Kb   = Qb + 8388608;          // 8388608
  u16* Vtb  = Kb + 8388608;          // 8388608

  const float CC = 0.18033688011112042f;  // log2(e)/sqrt(HD=64)

  k_convert<<<dim3(2048, 2), 256, 0, stream>>>(hs, ctx, hsb, ctxb);
  k_transW<<<dim3(16, 16, 3), 256, 0, stream>>>(Wq, Wk, Wv, Wt);
  k_gemm<<<dim3(64, 8, 3), 256, 0, stream>>>(hsb, ctxb, Wt, bq, bk, bv, Qb, Kb, Vtb, CC);
  k_attn<<<dim3(16, 64), 256, 0, stream>>>(Qb, Kb, Vtb, out);
}